// Round 10
// baseline (335.820 us; speedup 1.0000x reference)
//
#include <hip/hip_runtime.h>
#include <stdint.h>

typedef __attribute__((ext_vector_type(4))) float f32x4;
typedef __attribute__((ext_vector_type(8))) __bf16 bf16x8;
typedef __attribute__((ext_vector_type(4))) __bf16 bf16x4;

#define NB 2
#define NS 2048
#define ND 2048
#define NH 16
#define NHD 128
#define NM (NB*NS)      // 4096 rows
#define NQKV (3*ND)     // 6144

__device__ __forceinline__ short f2bf(float f) {
  union { float f; uint32_t u; } c; c.f = f;
  uint32_t r = (c.u + 0x7FFFu + ((c.u >> 16) & 1u)) >> 16;
  return (short)r;
}

__device__ __forceinline__ void gl_lds16(const short* g, short* l) {
  __builtin_amdgcn_global_load_lds(
      (const __attribute__((address_space(1))) void*)g,
      (__attribute__((address_space(3))) void*)l, 16, 0, 0);
}

// ---------------- fp32 -> bf16 elementwise ----------------
__global__ __launch_bounds__(256) void cvt_bf16_kernel(const float* __restrict__ in,
                                                       short* __restrict__ out, int n4) {
  int i = blockIdx.x * 256 + threadIdx.x;
  if (i >= n4) return;
  float4 v = ((const float4*)in)[i];
  short4 o;
  o.x = f2bf(v.x); o.y = f2bf(v.y); o.z = f2bf(v.z); o.w = f2bf(v.w);
  ((short4*)out)[i] = o;
}

// ---------------- fp32 [rows][cols] -> bf16 [cols][rows] ----------------
__global__ __launch_bounds__(256) void transpose_cvt_kernel(const float* __restrict__ in,
                                                            short* __restrict__ out,
                                                            int rows, int cols) {
  __shared__ float tile[64][65];
  const int tx = threadIdx.x, ty = threadIdx.y;
  const int r0 = blockIdx.y * 64, c0 = blockIdx.x * 64;
  for (int i = ty; i < 64; i += 4)
    tile[i][tx] = in[(size_t)(r0 + i) * cols + c0 + tx];
  __syncthreads();
  for (int i = ty; i < 64; i += 4)
    out[(size_t)(c0 + i) * rows + r0 + tx] = f2bf(tile[tx][i]);
}

// ---------------- bf16 GEMM, m201-faithful: BM=256, BN=64*NF, BK=64 ----------------
// 8 waves (2M x 4N), wave-tile 128 x 16*NF, acc[8][NF]. 4 phases per K-tile:
// {ds-read this phase's frags || stage one 64-row chunk -> barrier -> lgkmcnt(0)
//  -> setprio(1) MFMA cluster setprio(0) -> barrier}. vmcnt(NF) once per tile (ph4).
// A(t+1) staged ph1/ph2 into other buf; B(t+2) staged ph3/ph4 into current buf.
template<int EPI, int NF>
__global__ __launch_bounds__(512, 2) void gemm_kernel(
    const short* __restrict__ A, const short* __restrict__ Bt, int K, int N, int nbx,
    const float* __restrict__ bias,
    short* __restrict__ Qb, short* __restrict__ Kb, short* __restrict__ Vtb,
    const float* __restrict__ residual, float* __restrict__ out) {
  constexpr int NF0 = NF / 2, NF1 = NF - NF / 2;
  const int tid = threadIdx.x;
  const int wid = tid >> 6, l = tid & 63;
  const int l15 = l & 15, l4 = l >> 4;
  const int wr = wid >> 2, wc = wid & 3;

  // T1: XCD-contiguous chunks (grid % 8 == 0 -> bijective), bx fastest within chunk
  const int NTg = gridDim.x;
  const int flat = blockIdx.x;
  const int swz = (flat & 7) * (NTg >> 3) + (flat >> 3);
  const int bx = swz % nbx, by = swz / nbx;
  const int rowBase = by * 256, colBase = bx * (64 * NF);

  __shared__ short As[2][256 * 64];          // 64 KB
  __shared__ short Bs[2][64 * NF * 64];      // NF4: 64 KB, NF2: 32 KB

  f32x4 acc[8][NF] = {};
  const int nk = K >> 6;

  // staging: 1 inst = one 64-row x 128B chunk; LDS dest linear,
  // source col pre-swizzled (T2 both-sides rule, conflicts measured 0)
  const int crow = wid * 8 + (l >> 3);
  const int scol = ((l & 7) ^ ((l >> 3) & 7)) << 3;

#define STGC(ldsArr, buf, row0, gptr, gbase, kt0)                                \
    gl_lds16((gptr) + (size_t)((gbase) + (row0) + crow) * K + (size_t)(kt0) * 64 + scol, \
             &(ldsArr)[buf][((row0) + wid * 8) * 64])

  bf16x8 af[4][2], bf0[NF0][2], bf1[NF1][2];
  const int aXor = (l15 & 7) << 4;
  const int aColB = l4 * 16;

#define LDA(buf, mh)                                                             \
  _Pragma("unroll")                                                              \
  for (int m_ = 0; m_ < 4; ++m_) {                                               \
    const int r_ = wr * 128 + (mh) * 64 + m_ * 16 + l15;                         \
    _Pragma("unroll")                                                            \
    for (int kk_ = 0; kk_ < 2; ++kk_)                                            \
      af[m_][kk_] = *(const bf16x8*)((const char*)&As[buf][0] + r_ * 128 +       \
                                     ((kk_ * 64 + aColB) ^ aXor));               \
  }
#define LDB(buf, n0, cnt, dst)                                                   \
  _Pragma("unroll")                                                              \
  for (int n_ = 0; n_ < (cnt); ++n_) {                                           \
    const int r_ = wc * (16 * NF) + ((n0) + n_) * 16 + l15;                      \
    _Pragma("unroll")                                                            \
    for (int kk_ = 0; kk_ < 2; ++kk_)                                            \
      dst[n_][kk_] = *(const bf16x8*)((const char*)&Bs[buf][0] + r_ * 128 +      \
                                      ((kk_ * 64 + aColB) ^ aXor));              \
  }
#define MMAC(mh, n0, cnt, bsrc)                                                  \
  _Pragma("unroll")                                                              \
  for (int m_ = 0; m_ < 4; ++m_)                                                 \
    _Pragma("unroll")                                                            \
    for (int n_ = 0; n_ < (cnt); ++n_)                                           \
      _Pragma("unroll")                                                          \
      for (int kk_ = 0; kk_ < 2; ++kk_)                                          \
        acc[(mh) * 4 + m_][(n0) + n_] = __builtin_amdgcn_mfma_f32_16x16x32_bf16( \
            af[m_][kk_], bsrc[n_][kk_], acc[(mh) * 4 + m_][(n0) + n_], 0, 0, 0);

#define BAR       __builtin_amdgcn_s_barrier()
#define SCB       __builtin_amdgcn_sched_barrier(0)
#define LGKM0     asm volatile("s_waitcnt lgkmcnt(0)" ::: "memory")
#define PH_MMA(mh, n0, cnt, bsrc) do {                                           \
    BAR; LGKM0; SCB;                                                             \
    __builtin_amdgcn_s_setprio(1);                                               \
    MMAC(mh, n0, cnt, bsrc);                                                     \
    __builtin_amdgcn_s_setprio(0);                                               \
    SCB; BAR; SCB; } while (0)

#define STG_B_LO(buf, kt0) do { STGC(Bs, buf, 0, Bt, colBase, kt0);              \
    if (NF == 4) STGC(Bs, buf, 64, Bt, colBase, kt0); } while (0)
#define STG_B_HI(buf, kt0) do {                                                  \
    if (NF == 4) { STGC(Bs, buf, 128, Bt, colBase, kt0);                         \
                   STGC(Bs, buf, 192, Bt, colBase, kt0); }                       \
    else STGC(Bs, buf, 64, Bt, colBase, kt0); } while (0)

  // prologue: A(0),B(0) -> buf0; B(1) -> buf1. Wait A(0)+B(0) (leave B(1) flying).
  STGC(As, 0, 0, A, rowBase, 0); STGC(As, 0, 64, A, rowBase, 0);
  STGC(As, 0, 128, A, rowBase, 0); STGC(As, 0, 192, A, rowBase, 0);
  STG_B_LO(0, 0); STG_B_HI(0, 0);
  STG_B_LO(1, 1); STG_B_HI(1, 1);
  if (NF == 4) { asm volatile("s_waitcnt vmcnt(4)" ::: "memory"); }
  else         { asm volatile("s_waitcnt vmcnt(2)" ::: "memory"); }
  BAR; SCB;

  for (int t = 0; t < nk; ++t) {
    const int cur = t & 1;
    const bool stA = (t + 1 < nk);
    const bool stB = (t + 2 < nk);
    // ph1: read A-mh0 (8) + B-lo (2*NF0); stage A chunks 0,64 of t+1 -> other buf
    LDA(cur, 0); LDB(cur, 0, NF0, bf0);
    if (stA) { STGC(As, cur ^ 1, 0, A, rowBase, t + 1);
               STGC(As, cur ^ 1, 64, A, rowBase, t + 1); }
    PH_MMA(0, 0, NF0, bf0);
    // ph2: read B-hi (2*NF1); stage A chunks 128,192 of t+1
    LDB(cur, NF0, NF1, bf1);
    if (stA) { STGC(As, cur ^ 1, 128, A, rowBase, t + 1);
               STGC(As, cur ^ 1, 192, A, rowBase, t + 1); }
    PH_MMA(0, NF0, NF1, bf1);
    // ph3: read A-mh1 (8); stage B-lo of t+2 -> current buf (B region dead after ph2)
    LDA(cur, 1);
    if (stB) STG_B_LO(cur, t + 2);
    PH_MMA(1, NF0, NF1, bf1);
    // ph4: no reads (reuse bf0); stage B-hi of t+2; counted vmcnt -> tile t+1 landed
    if (stB) {
      STG_B_HI(cur, t + 2);
      if (NF == 4) { asm volatile("s_waitcnt vmcnt(4)" ::: "memory"); }
      else         { asm volatile("s_waitcnt vmcnt(2)" ::: "memory"); }
    } else {
      asm volatile("s_waitcnt vmcnt(0)" ::: "memory");
    }
    PH_MMA(1, 0, NF0, bf0);
  }
#undef STGC
#undef LDA
#undef LDB
#undef MMAC
#undef BAR
#undef SCB
#undef LGKM0
#undef PH_MMA
#undef STG_B_LO
#undef STG_B_HI

#pragma unroll
  for (int m = 0; m < 8; ++m) {
#pragma unroll
    for (int n = 0; n < NF; ++n) {
#pragma unroll
      for (int r = 0; r < 4; ++r) {
        const int row = rowBase + wr * 128 + m * 16 + l4 * 4 + r;
        const int col = colBase + wc * (16 * NF) + n * 16 + l15;
        float v = acc[m][n][r] + bias[col];
        if (EPI == 0) {
          const int h = col / 384;
          const int sub = col - h * 384;
          const int t = sub >> 7, hd = sub & 127;
          const int bb = row >> 11, s = row & 2047;
          const size_t bh = (size_t)bb * NH + h;
          if (t == 0)      Qb[(bh * NS + s) * NHD + hd] = f2bf(v * 0.08838834764831845f);
          else if (t == 1) Kb[(bh * NS + s) * NHD + hd] = f2bf(v);
          else             Vtb[(bh * NHD + hd) * NS + s] = f2bf(v);
        } else {
          const size_t idx = (size_t)row * N + col;
          out[idx] = v + residual[idx];
        }
      }
    }
  }
}

// ---------------- flash attention v4: QBLK=32/wave, K in LDS (swizzled) ----------------
__global__ __launch_bounds__(256, 2) void attn_kernel(
    const short* __restrict__ Qb, const short* __restrict__ Kb,
    const short* __restrict__ Vtb, const float* __restrict__ alibi,
    const int* __restrict__ amask, short* __restrict__ Ob) {
  const int tid = threadIdx.x;
  const int w = tid >> 6, l = tid & 63;
  const int l15 = l & 15, l4 = l >> 4;
  const int flat = blockIdx.x;
  const int bh = flat & 31;
  const int y = (flat >> 5) & 7, z = flat >> 8;
  const int qt = z ? (15 - y) : y;
  const int bb = bh >> 4, h = bh & 15;
  const int q0 = qt * 128;
  const int qw = q0 + w * 32;
  const int NT = 2 * qt + 2;

  __shared__ float biasLds[NS];
  __shared__ short Ks[2][64 * 128];
  __shared__ short Plds[4][32 * 64];

  {
    const float* abase = alibi + (size_t)bh * NS;
    const int* mbase = amask + (size_t)bb * NS;
    for (int i = tid; i < NS; i += 256)
      biasLds[i] = mbase[i] ? abase[i] : -1e30f;
  }

  const short* kbase = Kb + (size_t)bh * NS * NHD;
  const short* vbase = Vtb + (size_t)bh * NHD * NS;

#define KSTAGE(buf, kt0) do {                                                  \
    _Pragma("unroll")                                                          \
    for (int i_ = 0; i_ < 4; ++i_) {                                           \
      const int Lb_ = w * 4096 + i_ * 1024 + l * 16;                           \
      const int row_ = Lb_ >> 8;                                               \
      const int X_ = (Lb_ & 255) ^ ((row_ & 7) << 4);                          \
      gl_lds16((const short*)((const char*)kbase + (size_t)((kt0) * 64 + row_) * 256 + X_), \
               (short*)((char*)&Ks[buf][0] + (w * 4096 + i_ * 1024)));         \
    }                                                                          \
  } while (0)

  const short* qp = Qb + ((size_t)bh * NS + qw + l15) * NHD + l4 * 8;
  bf16x8 qf[2][4];
#pragma unroll
  for (int c = 0; c < 2; ++c)
#pragma unroll
    for (int s = 0; s < 4; ++s)
      qf[c][s] = *(const bf16x8*)(qp + c * 16 * NHD + s * 32);

  f32x4 acc[2][8] = {};
  float mrun[2] = {-1e30f, -1e30f}, lrun[2] = {0.f, 0.f};

  short* myP = &Plds[w][0];
  const int pswzB = (l15 & 7) << 4;
  const int qg0 = qw + l15, qg1 = qw + 16 + l15;

  KSTAGE(0, 0);
  __syncthreads();
  int cur = 0;

  for (int t = 0; t < NT; ++t) {
    const int k0 = t << 6;
    if (t + 1 < NT) KSTAGE(cur ^ 1, t + 1);

    if (k0 <= qw + 31) {
      f32x4 sT[2][4] = {};
      __builtin_amdgcn_s_setprio(1);
#pragma unroll
      for (int p = 0; p < 4; ++p) {
        const int lrow = p * 16 + l15;
#pragma unroll
        for (int s = 0; s < 4; ++s) {
          const int lbyte = (lrow << 8) + ((s * 64 + l4 * 16) ^ ((lrow & 7) << 4));
          const bf16x8 kf = *(const bf16x8*)((const char*)&Ks[cur][0] + lbyte);
          sT[0][p] = __builtin_amdgcn_mfma_f32_16x16x32_bf16(kf, qf[0][s], sT[0][p], 0, 0, 0);
          sT[1][p] = __builtin_amdgcn_mfma_f32_16x16x32_bf16(kf, qf[1][s], sT[1][p], 0, 0, 0);
        }
      }
      __builtin_amdgcn_s_setprio(0);

      const short* vp = vbase + (size_t)l15 * NS + k0 + l4 * 8;
      bf16x8 vA[8];
#pragma unroll
      for (int t8 = 0; t8 < 8; ++t8)
        vA[t8] = *(const bf16x8*)(vp + (size_t)t8 * 16 * NS);

      const bool full = (k0 + 63 <= qw);
      float pv[2][16];
      float tmax[2] = {-1e30f, -1e30f};
#pragma unroll
      for (int p = 0; p < 4; ++p) {
        const f32x4 bvec = *(const f32x4*)&biasLds[k0 + p * 16 + l4 * 4];
#pragma unroll
        for (int r = 0; r < 4; ++r) {
          const int kg = k0 + p * 16 + l4 * 4 + r;
          float v0 = sT[0][p][r] + bvec[r];
          float v1 = sT[1][p][r] + bvec[r];
          if (!full) {
            v0 = (kg <= qg0) ? v0 : -1e30f;
            v1 = (kg <= qg1) ? v1 : -1e30f;
          }
          pv[0][p * 4 + r] = v0; pv[1][p * 4 + r] = v1;
          tmax[0] = fmaxf(tmax[0], v0);
          tmax[1] = fmaxf(tmax[1], v1);
        }
      }
      float alpha[2];
#pragma unroll
      for (int c = 0; c < 2; ++c) {
        tmax[c] = fmaxf(tmax[c], __shfl_xor(tmax[c], 16, 64));
        tmax[c] = fmaxf(tmax[c], __shfl_xor(tmax[c], 32, 64));
        const float mnew = fmaxf(mrun[c], tmax[c]);
        alpha[c] = __expf(mrun[c] - mnew);
        mrun[c] = mnew;
        float psum = 0.f;
#pragma unroll
        for (int i = 0; i < 16; ++i) {
          pv[c][i] = __expf(pv[c][i] - mnew);
          psum += pv[c][i];
        }
        psum += __shfl_xor(psum, 16, 64);
        psum += __shfl_xor(psum, 32, 64);
        lrun[c] = lrun[c] * alpha[c] + psum;
#pragma unroll
        for (int t8 = 0; t8 < 8; ++t8)
#pragma unroll
          for (int r = 0; r < 4; ++r)
            acc[c][t8][r] *= alpha[c];
      }

#pragma unroll
      for (int c = 0; c < 2; ++c)
#pragma unroll
        for (int p = 0; p < 4; ++p) {
          bf16x4 pk = { (__bf16)pv[c][p * 4 + 0], (__bf16)pv[c][p * 4 + 1],
                        (__bf16)pv[c][p * 4 + 2], (__bf16)pv[c][p * 4 + 3] };
          const int byteoff = ((16 * c + l15) << 7) + (((p * 16 + l4 * 4) << 1) ^ pswzB);
          *(bf16x4*)((char*)myP + byteoff) = pk;
        }
      asm volatile("s_waitcnt lgkmcnt(0)" ::: "memory");

      bf16x8 pfA[2], pfB[2];
#pragma unroll
      for (int c = 0; c < 2; ++c)
        pfA[c] = *(const bf16x8*)((const char*)myP + ((16 * c + l15) << 7) + ((l4 * 16) ^ pswzB));
      bf16x8 vB[8];
#pragma unroll
      for (int t8 = 0; t8 < 8; ++t8)
        vB[t8] = *(const bf16x8*)(vp + 32 + (size_t)t8 * 16 * NS);
      __builtin_amdgcn_s_setprio(1);
#pragma unroll
      for (int t8 = 0; t8 < 8; ++t8) {
        acc[0][t8] = __builtin_amdgcn_mfma_f32_16x16x32_bf16(vA[t8], pfA[0], acc[0][t8], 0, 0, 0);
        acc[1][t8] = __builtin_amdgcn_mfma_f32_16x16x32_bf16(vA[t8], pfA[1], acc[1][t8], 0, 0, 0);
      }
      __builtin_amdgcn_s_setprio(0);
#pragma unroll
      for (int c = 0; c < 2; ++c)
        pfB[c] = *(const bf16x8*)((const char*)myP + ((16 * c + l15) << 7) + ((64 + l4 * 16) ^ pswzB));
      __builtin_amdgcn_s_setprio(1);
#pragma unroll
      for (int t8 = 0; t8 < 8; ++t8) {
        acc[0][t8] = __builtin_amdgcn_mfma_f32_16x16x32_bf16(vB[t8], pfB[0], acc[0][t8], 0, 0, 0);
        acc[1][t8] = __builtin_amdgcn_mfma_f32_16x16x32_bf16(vB[t8], pfB[1], acc[1][t8], 0, 0, 0);
      }
      __builtin_amdgcn_s_setprio(0);
    }

    __syncthreads();
    cur ^= 1;
  }
#undef KSTAGE

#pragma unroll
  for (int c = 0; c < 2; ++c) {
    const float inv = (lrun[c] > 0.f) ? 1.0f / lrun[c] : 0.f;
    short* obase = Ob + ((size_t)bb * NS + qw + 16 * c + l15) * ND + h * NHD + l4 * 4;
#pragma unroll
    for (int t8 = 0; t8 < 8; ++t8) {
      bf16x4 o = { (__bf16)(acc[c][t8][0] * inv), (__bf16)(acc[c][t8][1] * inv),
                   (__bf16)(acc[c][t8][2] * inv), (__bf16)(acc[c][t8][3] * inv) };
      *(bf16x4*)&obase[t8 * 16] = o;
    }
  }
}

extern "C" void kernel_launch(void* const* d_in, const int* in_sizes, int n_in,
                              void* d_out, int out_size, void* d_ws, size_t ws_size,
                              hipStream_t stream) {
  const float* hidden   = (const float*)d_in[0];
  const float* residual = (const float*)d_in[1];
  const float* alibi    = (const float*)d_in[2];
  const float* W_qkv    = (const float*)d_in[3];
  const float* b_qkv    = (const float*)d_in[4];
  const float* W_o      = (const float*)d_in[5];
  const float* b_o      = (const float*)d_in[6];
  const int*   amask    = (const int*)d_in[7];
  float* out = (float*)d_out;

  char* p = (char*)d_ws;
  short* Abuf  = (short*)p; p += (size_t)NM * ND * 2;
  short* WqkvT = (short*)p; p += (size_t)NQKV * ND * 2;
  short* WoT   = (short*)p; p += (size_t)ND * ND * 2;
  short* Qb    = (short*)p; p += (size_t)NB * NH * NS * NHD * 2;
  short* Kb    = (short*)p; p += (size_t)NB * NH * NS * NHD * 2;
  short* Vtb   = (short*)p; p += (size_t)NB * NH * NS * NHD * 2;
  short* Ob    = (short*)p; p += (size_t)NM * ND * 2;

  cvt_bf16_kernel<<<(NM * ND / 4) / 256, 256, 0, stream>>>(hidden, Abuf, NM * ND / 4);
  transpose_cvt_kernel<<<dim3(NQKV / 64, ND / 64), dim3(64, 4), 0, stream>>>(W_qkv, WqkvT, ND, NQKV);
  transpose_cvt_kernel<<<dim3(ND / 64, ND / 64), dim3(64, 4), 0, stream>>>(W_o, WoT, ND, ND);
  // QKV: BM=256, BN=256 (NF=4): grid 16*24 = 384 (%8==0)
  gemm_kernel<0, 4><<<dim3((NM / 256) * (NQKV / 256)), 512, 0, stream>>>(
      Abuf, WqkvT, ND, NQKV, NQKV / 256, b_qkv, Qb, Kb, Vtb, nullptr, nullptr);
  attn_kernel<<<dim3(512), 256, 0, stream>>>(Qb, Kb, Vtb, alibi, amask, Ob);
  // O-proj: BM=256, BN=128 (NF=2): grid 16*16 = 256 -> exactly 1 pass
  gemm_kernel<1, 2><<<dim3((NM / 256) * (ND / 128)), 512, 0, stream>>>(
      Ob, WoT, ND, ND, ND / 128, b_o, nullptr, nullptr, nullptr, residual, out);
}

// Round 11
// 324.015 us; speedup vs baseline: 1.0364x; 1.0364x over previous
//
#include <hip/hip_runtime.h>
#include <stdint.h>

typedef __attribute__((ext_vector_type(4))) float f32x4;
typedef __attribute__((ext_vector_type(8))) __bf16 bf16x8;
typedef __attribute__((ext_vector_type(4))) __bf16 bf16x4;

#define NB 2
#define NS 2048
#define ND 2048
#define NH 16
#define NHD 128
#define NM (NB*NS)      // 4096 rows
#define NQKV (3*ND)     // 6144

__device__ __forceinline__ short f2bf(float f) {
  union { float f; uint32_t u; } c; c.f = f;
  uint32_t r = (c.u + 0x7FFFu + ((c.u >> 16) & 1u)) >> 16;
  return (short)r;
}

__device__ __forceinline__ void gl_lds16(const short* g, short* l) {
  __builtin_amdgcn_global_load_lds(
      (const __attribute__((address_space(1))) void*)g,
      (__attribute__((address_space(3))) void*)l, 16, 0, 0);
}

// ---------------- fp32 -> bf16 elementwise ----------------
__global__ __launch_bounds__(256) void cvt_bf16_kernel(const float* __restrict__ in,
                                                       short* __restrict__ out, int n4) {
  int i = blockIdx.x * 256 + threadIdx.x;
  if (i >= n4) return;
  float4 v = ((const float4*)in)[i];
  short4 o;
  o.x = f2bf(v.x); o.y = f2bf(v.y); o.z = f2bf(v.z); o.w = f2bf(v.w);
  ((short4*)out)[i] = o;
}

// ---------------- fp32 [rows][cols] -> bf16 [cols][rows] ----------------
__global__ __launch_bounds__(256) void transpose_cvt_kernel(const float* __restrict__ in,
                                                            short* __restrict__ out,
                                                            int rows, int cols) {
  __shared__ float tile[64][65];
  const int tx = threadIdx.x, ty = threadIdx.y;
  const int r0 = blockIdx.y * 64, c0 = blockIdx.x * 64;
  for (int i = ty; i < 64; i += 4)
    tile[i][tx] = in[(size_t)(r0 + i) * cols + c0 + tx];
  __syncthreads();
  for (int i = ty; i < 64; i += 4)
    out[(size_t)(c0 + i) * rows + r0 + tx] = f2bf(tile[tx][i]);
}

// ---------------- bf16 GEMM, 128x128, BK=64, 4 waves (2x2), 2 blocks/CU ----------------
// Reg-pipelined 2-phase K-loop (round-8 schedule) at 64KB LDS so TWO independent
// blocks co-reside per CU: one block's barrier/lgkm/vmcnt drains overlap the other
// block's MFMA (m97/m114 implicit overlap). Counted waits: P0 lgkm(4), P1 lgkm(12),
// one vmcnt(4) per tile. T2 swizzle (linear LDS dest + pre-swizzled source + XOR read).
template<int EPI>
__global__ __launch_bounds__(256, 2) void gemm_kernel(
    const short* __restrict__ A, const short* __restrict__ Bt, int K, int N, int nbx,
    const float* __restrict__ bias,
    short* __restrict__ Qb, short* __restrict__ Kb, short* __restrict__ Vtb,
    const float* __restrict__ residual, float* __restrict__ out) {
  const int tid = threadIdx.x;
  const int wid = tid >> 6, l = tid & 63;
  const int l15 = l & 15, l4 = l >> 4;
  const int wr = wid >> 1, wc = wid & 1;

  // T1: XCD-contiguous chunks (grid % 8 == 0 -> bijective), bx fastest
  const int NTg = gridDim.x;
  const int flat = blockIdx.x;
  const int swz = (flat & 7) * (NTg >> 3) + (flat >> 3);
  const int bx = swz % nbx, by = swz / nbx;
  const int rowBase = by * 128, colBase = bx * 128;

  __shared__ short As[2][128 * 64];   // 32 KB
  __shared__ short Bs[2][128 * 64];   // 32 KB

  f32x4 acc[4][4] = {};
  const int nk = K >> 6;

  // staging: chunk ci = 32 rows x 128B = one gl_lds16 per block (256 lanes x 16B);
  // LDS dest linear; source col-slot pre-swizzled (T2 both-sides, conflicts = 0)
  const int crow = tid >> 3;                         // 0..31 within chunk
  const int scol = ((tid & 7) ^ ((tid >> 3) & 7)) << 3;  // swizzled source col (elems)

#define STGC(ldsArr, buf, ci, gptr, gbase, kt0)                                  \
    gl_lds16((gptr) + (size_t)((gbase) + (ci) * 32 + crow) * K +                 \
                 (size_t)(kt0) * 64 + scol,                                      \
             &(ldsArr)[buf][((ci) * 32 + wid * 8) * 64])
#define STG_A(buf, kt0) do { STGC(As, buf, 0, A, rowBase, kt0);                  \
    STGC(As, buf, 1, A, rowBase, kt0); STGC(As, buf, 2, A, rowBase, kt0);        \
    STGC(As, buf, 3, A, rowBase, kt0); } while (0)
#define STG_B(buf, kt0) do { STGC(Bs, buf, 0, Bt, colBase, kt0);                 \
    STGC(Bs, buf, 1, Bt, colBase, kt0); STGC(Bs, buf, 2, Bt, colBase, kt0);      \
    STGC(Bs, buf, 3, Bt, colBase, kt0); } while (0)

  bf16x8 afS0[4][2], afS1[4][2], bfLo[2][2], bfHi[2][2];
  const int aXor = (l15 & 7) << 4;   // byte XOR; frag row & 7 == l15 & 7
  const int aColB = l4 * 16;

#define LDA(buf, DST)                                                            \
  _Pragma("unroll")                                                              \
  for (int m_ = 0; m_ < 4; ++m_) {                                               \
    const int r_ = wr * 64 + m_ * 16 + l15;                                      \
    _Pragma("unroll")                                                            \
    for (int kk_ = 0; kk_ < 2; ++kk_)                                            \
      DST[m_][kk_] = *(const bf16x8*)((const char*)&As[buf][0] + r_ * 128 +      \
                                      ((kk_ * 64 + aColB) ^ aXor));              \
  }
#define LDBn(buf, DST, nb)                                                       \
  _Pragma("unroll")                                                              \
  for (int n_ = 0; n_ < 2; ++n_) {                                               \
    const int r_ = wc * 64 + ((nb) + n_) * 16 + l15;                             \
    _Pragma("unroll")                                                            \
    for (int kk_ = 0; kk_ < 2; ++kk_)                                            \
      DST[n_][kk_] = *(const bf16x8*)((const char*)&Bs[buf][0] + r_ * 128 +      \
                                      ((kk_ * 64 + aColB) ^ aXor));              \
  }
#define MMAQ(AF, BF, nb)                                                         \
  _Pragma("unroll")                                                              \
  for (int m_ = 0; m_ < 4; ++m_)                                                 \
    _Pragma("unroll")                                                            \
    for (int n_ = 0; n_ < 2; ++n_)                                               \
      _Pragma("unroll")                                                          \
      for (int kk_ = 0; kk_ < 2; ++kk_)                                          \
        acc[m_][(nb) + n_] = __builtin_amdgcn_mfma_f32_16x16x32_bf16(            \
            AF[m_][kk_], BF[n_][kk_], acc[m_][(nb) + n_], 0, 0, 0);

  // Per K-tile, two phases. AFc = this tile's A regs (loaded last tile's P1).
  // P0: read bfHi(cur)[4 ds]; stage A(t+2); lgkm(4) [drain prev 12]; MMA half0;
  //     vmcnt(4) [tile t+1 landed, A(t+2) flying]; barrier.
  // P1: read A(t+1)->AFn + bfLo(t+1) [12 ds]; stage B(t+2); lgkm(12) [drain 4];
  //     MMA half1; barrier.
#define TILE(kt, AFc, AFn, cur)                                                  \
  do {                                                                           \
    const bool stA = (kt) + 2 < nk;                                              \
    const bool nxt = (kt) + 1 < nk;                                              \
    LDBn(cur, bfHi, 2);                                                          \
    if (stA) STG_A(cur, (kt) + 2);                                               \
    asm volatile("s_waitcnt lgkmcnt(4)" ::: "memory");                           \
    __builtin_amdgcn_sched_barrier(0);                                           \
    __builtin_amdgcn_s_setprio(1);                                               \
    MMAQ(AFc, bfLo, 0);                                                          \
    __builtin_amdgcn_s_setprio(0);                                               \
    __builtin_amdgcn_sched_barrier(0);                                           \
    if (stA)      { asm volatile("s_waitcnt vmcnt(4)" ::: "memory"); }           \
    else if (nxt) { asm volatile("s_waitcnt vmcnt(0)" ::: "memory"); }           \
    __builtin_amdgcn_s_barrier();                                                \
    if (nxt) { LDA(cur ^ 1, AFn); LDBn(cur ^ 1, bfLo, 0); }                      \
    if (stA) STG_B(cur, (kt) + 2);                                               \
    if (nxt) { asm volatile("s_waitcnt lgkmcnt(12)" ::: "memory"); }             \
    else     { asm volatile("s_waitcnt lgkmcnt(0)"  ::: "memory"); }             \
    __builtin_amdgcn_sched_barrier(0);                                           \
    __builtin_amdgcn_s_setprio(1);                                               \
    MMAQ(AFc, bfHi, 2);                                                          \
    __builtin_amdgcn_s_setprio(0);                                               \
    __builtin_amdgcn_sched_barrier(0);                                           \
    __builtin_amdgcn_s_barrier();                                                \
  } while (0)

  // prologue: prime tiles 0,1; wait tile 0 (leave tile 1's 8 in flight); first reads
  STG_A(0, 0); STG_B(0, 0);
  STG_A(1, 1); STG_B(1, 1);
  asm volatile("s_waitcnt vmcnt(8)" ::: "memory");
  __builtin_amdgcn_s_barrier();
  LDA(0, afS0); LDBn(0, bfLo, 0);   // 12 ds outstanding entering TILE(0) P0

  for (int kt = 0; kt < nk; kt += 2) {
    TILE(kt,     afS0, afS1, 0);
    TILE(kt + 1, afS1, afS0, 1);
  }
#undef STGC
#undef STG_A
#undef STG_B
#undef LDA
#undef LDBn
#undef MMAQ
#undef TILE

#pragma unroll
  for (int m = 0; m < 4; ++m) {
#pragma unroll
    for (int n = 0; n < 4; ++n) {
#pragma unroll
      for (int r = 0; r < 4; ++r) {
        const int row = rowBase + wr * 64 + m * 16 + l4 * 4 + r;
        const int col = colBase + wc * 64 + n * 16 + l15;
        float v = acc[m][n][r] + bias[col];
        if (EPI == 0) {
          const int h = col / 384;
          const int sub = col - h * 384;
          const int t = sub >> 7, hd = sub & 127;
          const int bb = row >> 11, s = row & 2047;
          const size_t bh = (size_t)bb * NH + h;
          if (t == 0)      Qb[(bh * NS + s) * NHD + hd] = f2bf(v * 0.08838834764831845f);
          else if (t == 1) Kb[(bh * NS + s) * NHD + hd] = f2bf(v);
          else             Vtb[(bh * NHD + hd) * NS + s] = f2bf(v);
        } else {
          const size_t idx = (size_t)row * N + col;
          out[idx] = v + residual[idx];
        }
      }
    }
  }
}

// ---------------- flash attention v4: QBLK=32/wave, K in LDS (swizzled) ----------------
__global__ __launch_bounds__(256, 2) void attn_kernel(
    const short* __restrict__ Qb, const short* __restrict__ Kb,
    const short* __restrict__ Vtb, const float* __restrict__ alibi,
    const int* __restrict__ amask, short* __restrict__ Ob) {
  const int tid = threadIdx.x;
  const int w = tid >> 6, l = tid & 63;
  const int l15 = l & 15, l4 = l >> 4;
  const int flat = blockIdx.x;
  const int bh = flat & 31;
  const int y = (flat >> 5) & 7, z = flat >> 8;
  const int qt = z ? (15 - y) : y;
  const int bb = bh >> 4, h = bh & 15;
  const int q0 = qt * 128;
  const int qw = q0 + w * 32;
  const int NT = 2 * qt + 2;

  __shared__ float biasLds[NS];
  __shared__ short Ks[2][64 * 128];
  __shared__ short Plds[4][32 * 64];

  {
    const float* abase = alibi + (size_t)bh * NS;
    const int* mbase = amask + (size_t)bb * NS;
    for (int i = tid; i < NS; i += 256)
      biasLds[i] = mbase[i] ? abase[i] : -1e30f;
  }

  const short* kbase = Kb + (size_t)bh * NS * NHD;
  const short* vbase = Vtb + (size_t)bh * NHD * NS;

#define KSTAGE(buf, kt0) do {                                                  \
    _Pragma("unroll")                                                          \
    for (int i_ = 0; i_ < 4; ++i_) {                                           \
      const int Lb_ = w * 4096 + i_ * 1024 + l * 16;                           \
      const int row_ = Lb_ >> 8;                                               \
      const int X_ = (Lb_ & 255) ^ ((row_ & 7) << 4);                          \
      gl_lds16((const short*)((const char*)kbase + (size_t)((kt0) * 64 + row_) * 256 + X_), \
               (short*)((char*)&Ks[buf][0] + (w * 4096 + i_ * 1024)));         \
    }                                                                          \
  } while (0)

  const short* qp = Qb + ((size_t)bh * NS + qw + l15) * NHD + l4 * 8;
  bf16x8 qf[2][4];
#pragma unroll
  for (int c = 0; c < 2; ++c)
#pragma unroll
    for (int s = 0; s < 4; ++s)
      qf[c][s] = *(const bf16x8*)(qp + c * 16 * NHD + s * 32);

  f32x4 acc[2][8] = {};
  float mrun[2] = {-1e30f, -1e30f}, lrun[2] = {0.f, 0.f};

  short* myP = &Plds[w][0];
  const int pswzB = (l15 & 7) << 4;
  const int qg0 = qw + l15, qg1 = qw + 16 + l15;

  KSTAGE(0, 0);
  __syncthreads();
  int cur = 0;

  for (int t = 0; t < NT; ++t) {
    const int k0 = t << 6;
    if (t + 1 < NT) KSTAGE(cur ^ 1, t + 1);

    if (k0 <= qw + 31) {
      f32x4 sT[2][4] = {};
      __builtin_amdgcn_s_setprio(1);
#pragma unroll
      for (int p = 0; p < 4; ++p) {
        const int lrow = p * 16 + l15;
#pragma unroll
        for (int s = 0; s < 4; ++s) {
          const int lbyte = (lrow << 8) + ((s * 64 + l4 * 16) ^ ((lrow & 7) << 4));
          const bf16x8 kf = *(const bf16x8*)((const char*)&Ks[cur][0] + lbyte);
          sT[0][p] = __builtin_amdgcn_mfma_f32_16x16x32_bf16(kf, qf[0][s], sT[0][p], 0, 0, 0);
          sT[1][p] = __builtin_amdgcn_mfma_f32_16x16x32_bf16(kf, qf[1][s], sT[1][p], 0, 0, 0);
        }
      }
      __builtin_amdgcn_s_setprio(0);

      const short* vp = vbase + (size_t)l15 * NS + k0 + l4 * 8;
      bf16x8 vA[8];
#pragma unroll
      for (int t8 = 0; t8 < 8; ++t8)
        vA[t8] = *(const bf16x8*)(vp + (size_t)t8 * 16 * NS);

      const bool full = (k0 + 63 <= qw);
      float pv[2][16];
      float tmax[2] = {-1e30f, -1e30f};
#pragma unroll
      for (int p = 0; p < 4; ++p) {
        const f32x4 bvec = *(const f32x4*)&biasLds[k0 + p * 16 + l4 * 4];
#pragma unroll
        for (int r = 0; r < 4; ++r) {
          const int kg = k0 + p * 16 + l4 * 4 + r;
          float v0 = sT[0][p][r] + bvec[r];
          float v1 = sT[1][p][r] + bvec[r];
          if (!full) {
            v0 = (kg <= qg0) ? v0 : -1e30f;
            v1 = (kg <= qg1) ? v1 : -1e30f;
          }
          pv[0][p * 4 + r] = v0; pv[1][p * 4 + r] = v1;
          tmax[0] = fmaxf(tmax[0], v0);
          tmax[1] = fmaxf(tmax[1], v1);
        }
      }
      float alpha[2];
#pragma unroll
      for (int c = 0; c < 2; ++c) {
        tmax[c] = fmaxf(tmax[c], __shfl_xor(tmax[c], 16, 64));
        tmax[c] = fmaxf(tmax[c], __shfl_xor(tmax[c], 32, 64));
        const float mnew = fmaxf(mrun[c], tmax[c]);
        alpha[c] = __expf(mrun[c] - mnew);
        mrun[c] = mnew;
        float psum = 0.f;
#pragma unroll
        for (int i = 0; i < 16; ++i) {
          pv[c][i] = __expf(pv[c][i] - mnew);
          psum += pv[c][i];
        }
        psum += __shfl_xor(psum, 16, 64);
        psum += __shfl_xor(psum, 32, 64);
        lrun[c] = lrun[c] * alpha[c] + psum;
#pragma unroll
        for (int t8 = 0; t8 < 8; ++t8)
#pragma unroll
          for (int r = 0; r < 4; ++r)
            acc[c][t8][r] *= alpha[c];
      }

#pragma unroll
      for (int c = 0; c < 2; ++c)
#pragma unroll
        for (int p = 0; p < 4; ++p) {
          bf16x4 pk = { (__bf16)pv[c][p * 4 + 0], (__bf16)pv[c][p * 4 + 1],
                        (__bf16)pv[c][p * 4 + 2], (__bf16)pv[c][p * 4 + 3] };
          const int byteoff = ((16 * c + l15) << 7) + (((p * 16 + l4 * 4) << 1) ^ pswzB);
          *(bf16x4*)((char*)myP + byteoff) = pk;
        }
      asm volatile("s_waitcnt lgkmcnt(0)" ::: "memory");

      bf16x8 pfA[2], pfB[2];
#pragma unroll
      for (int c = 0; c < 2; ++c)
        pfA[c] = *(const bf16x8*)((const char*)myP + ((16 * c + l15) << 7) + ((l4 * 16) ^ pswzB));
      bf16x8 vB[8];
#pragma unroll
      for (int t8 = 0; t8 < 8; ++t8)
        vB[t8] = *(const bf16x8*)(vp + 32 + (size_t)t8 * 16 * NS);
      __builtin_amdgcn_s_setprio(1);
#pragma unroll
      for (int t8 = 0; t8 < 8; ++t8) {
        acc[0][t8] = __builtin_amdgcn_mfma_f32_16x16x32_bf16(vA[t8], pfA[0], acc[0][t8], 0, 0, 0);
        acc[1][t8] = __builtin_amdgcn_mfma_f32_16x16x32_bf16(vA[t8], pfA[1], acc[1][t8], 0, 0, 0);
      }
      __builtin_amdgcn_s_setprio(0);
#pragma unroll
      for (int c = 0; c < 2; ++c)
        pfB[c] = *(const bf16x8*)((const char*)myP + ((16 * c + l15) << 7) + ((64 + l4 * 16) ^ pswzB));
      __builtin_amdgcn_s_setprio(1);
#pragma unroll
      for (int t8 = 0; t8 < 8; ++t8) {
        acc[0][t8] = __builtin_amdgcn_mfma_f32_16x16x32_bf16(vB[t8], pfB[0], acc[0][t8], 0, 0, 0);
        acc[1][t8] = __builtin_amdgcn_mfma_f32_16x16x32_bf16(vB[t8], pfB[1], acc[1][t8], 0, 0, 0);
      }
      __builtin_amdgcn_s_setprio(0);
    }

    __syncthreads();
    cur ^= 1;
  }
#undef KSTAGE

#pragma unroll
  for (int c = 0; c < 2; ++c) {
    const float inv = (lrun[c] > 0.f) ? 1.0f / lrun[c] : 0.f;
    short* obase = Ob + ((size_t)bb * NS + qw + 16 * c + l15) * ND + h * NHD + l4 * 4;
#pragma unroll
    for (int t8 = 0; t8 < 8; ++t8) {
      bf16x4 o = { (__bf16)(acc[c][t8][0] * inv), (__bf16)(acc[c][t8][1] * inv),
                   (__bf16)(acc[c][t8][2] * inv), (__bf16)(acc[c][t8][3] * inv) };
      *(bf16x4*)&obase[t8 * 16] = o;
    }
  }
}

extern "C" void kernel_launch(void* const* d_in, const int* in_sizes, int n_in,
                              void* d_out, int out_size, void* d_ws, size_t ws_size,
                              hipStream_t stream) {
  const float* hidden   = (const float*)d_in[0];
  const float* residual = (const float*)d_in[1];
  const float* alibi    = (const float*)d_in[2];
  const float* W_qkv    = (const float*)d_in[3];
  const float* b_qkv    = (const float*)d_in[4];
  const float* W_o      = (const float*)d_in[5];
  const float* b_o      = (const float*)d_in[6];
  const int*   amask    = (const int*)d_in[7];
  float* out = (float*)d_out;

  char* p = (char*)d_ws;
  short* Abuf  = (short*)p; p += (size_t)NM * ND * 2;
  short* WqkvT = (short*)p; p += (size_t)NQKV * ND * 2;
  short* WoT   = (short*)p; p += (size_t)ND * ND * 2;
  short* Qb    = (short*)p; p += (size_t)NB * NH * NS * NHD * 2;
  short* Kb    = (short*)p; p += (size_t)NB * NH * NS * NHD * 2;
  short* Vtb   = (short*)p; p += (size_t)NB * NH * NS * NHD * 2;
  short* Ob    = (short*)p; p += (size_t)NM * ND * 2;

  cvt_bf16_kernel<<<(NM * ND / 4) / 256, 256, 0, stream>>>(hidden, Abuf, NM * ND / 4);
  transpose_cvt_kernel<<<dim3(NQKV / 64, ND / 64), dim3(64, 4), 0, stream>>>(W_qkv, WqkvT, ND, NQKV);
  transpose_cvt_kernel<<<dim3(ND / 64, ND / 64), dim3(64, 4), 0, stream>>>(W_o, WoT, ND, ND);
  // QKV: 128x128 tile, grid 32*48 = 1536 (%8==0), 2 blocks/CU, 3 balanced rounds
  gemm_kernel<0><<<dim3((NM / 128) * (NQKV / 128)), 256, 0, stream>>>(
      Abuf, WqkvT, ND, NQKV, NQKV / 128, b_qkv, Qb, Kb, Vtb, nullptr, nullptr);
  attn_kernel<<<dim3(512), 256, 0, stream>>>(Qb, Kb, Vtb, alibi, amask, Ob);
  // O-proj: grid 32*16 = 512, 2 blocks/CU, 1 round
  gemm_kernel<1><<<dim3((NM / 128) * (ND / 128)), 256, 0, stream>>>(
      Ob, WoT, ND, ND, ND / 128, b_o, nullptr, nullptr, nullptr, residual, out);
}

// Round 12
// 319.638 us; speedup vs baseline: 1.0506x; 1.0137x over previous
//
#include <hip/hip_runtime.h>
#include <stdint.h>

typedef __attribute__((ext_vector_type(4))) float f32x4;
typedef __attribute__((ext_vector_type(8))) __bf16 bf16x8;
typedef __attribute__((ext_vector_type(4))) __bf16 bf16x4;

#define NB 2
#define NS 2048
#define ND 2048
#define NH 16
#define NHD 128
#define NM (NB*NS)      // 4096 rows
#define NQKV (3*ND)     // 6144

__device__ __forceinline__ short f2bf(float f) {
  union { float f; uint32_t u; } c; c.f = f;
  uint32_t r = (c.u + 0x7FFFu + ((c.u >> 16) & 1u)) >> 16;
  return (short)r;
}

__device__ __forceinline__ void gl_lds16(const short* g, short* l) {
  __builtin_amdgcn_global_load_lds(
      (const __attribute__((address_space(1))) void*)g,
      (__attribute__((address_space(3))) void*)l, 16, 0, 0);
}

// ---------------- fused prepass: cvt hidden + transpose W_qkv + transpose W_o ----
// blocks [0,8192): hidden fp32 -> bf16 (float4/short4)
// blocks [8192,11264): W_qkv [2048][6144] -> WqkvT [6144][2048] bf16
// blocks [11264,12288): W_o [2048][2048] -> WoT bf16
__global__ __launch_bounds__(256) void prep_kernel(
    const float* __restrict__ hidden, short* __restrict__ Abuf,
    const float* __restrict__ W_qkv, short* __restrict__ WqkvT,
    const float* __restrict__ W_o, short* __restrict__ WoT) {
  __shared__ float tile[64][65];
  const int b = blockIdx.x;
  if (b < 8192) {
    const int i = b * 256 + threadIdx.x;
    float4 v = ((const float4*)hidden)[i];
    short4 o;
    o.x = f2bf(v.x); o.y = f2bf(v.y); o.z = f2bf(v.z); o.w = f2bf(v.w);
    ((short4*)Abuf)[i] = o;
  } else {
    const float* in; short* out; int cols, t;
    if (b < 11264) { in = W_qkv; out = WqkvT; cols = NQKV; t = b - 8192; }
    else           { in = W_o;   out = WoT;   cols = ND;   t = b - 11264; }
    const int rows = ND;
    const int nbx = cols >> 6;
    const int bx = t % nbx, by = t / nbx;
    const int tx = threadIdx.x & 63, ty = threadIdx.x >> 6;
    const int r0 = by * 64, c0 = bx * 64;
    for (int i = ty; i < 64; i += 4)
      tile[i][tx] = in[(size_t)(r0 + i) * cols + c0 + tx];
    __syncthreads();
    for (int i = ty; i < 64; i += 4)
      out[(size_t)(c0 + i) * rows + r0 + tx] = f2bf(tile[tx][i]);
  }
}

// ---------------- bf16 GEMM, 128x128, BK=64, 4 waves (2x2), 2 blocks/CU ----------------
// Reg-pipelined 2-phase K-loop; cross-block overlap hides barrier/waitcnt drains.
// At its structural LDS-read cap (~30% MfmaUtil): 0.5 b128-reads/MFMA at 64x64
// wave-tile; reads run at the 8 cy/instr LDS floor (conflicts = 0).
template<int EPI>
__global__ __launch_bounds__(256, 2) void gemm_kernel(
    const short* __restrict__ A, const short* __restrict__ Bt, int K, int N, int nbx,
    const float* __restrict__ bias,
    short* __restrict__ Qb, short* __restrict__ Kb, short* __restrict__ Vtb,
    const float* __restrict__ residual, float* __restrict__ out) {
  const int tid = threadIdx.x;
  const int wid = tid >> 6, l = tid & 63;
  const int l15 = l & 15, l4 = l >> 4;
  const int wr = wid >> 1, wc = wid & 1;

  const int NTg = gridDim.x;
  const int flat = blockIdx.x;
  const int swz = (flat & 7) * (NTg >> 3) + (flat >> 3);
  const int bx = swz % nbx, by = swz / nbx;
  const int rowBase = by * 128, colBase = bx * 128;

  __shared__ short As[2][128 * 64];   // 32 KB
  __shared__ short Bs[2][128 * 64];   // 32 KB

  f32x4 acc[4][4] = {};
  const int nk = K >> 6;

  const int crow = tid >> 3;
  const int scol = ((tid & 7) ^ ((tid >> 3) & 7)) << 3;

#define STGC(ldsArr, buf, ci, gptr, gbase, kt0)                                  \
    gl_lds16((gptr) + (size_t)((gbase) + (ci) * 32 + crow) * K +                 \
                 (size_t)(kt0) * 64 + scol,                                      \
             &(ldsArr)[buf][((ci) * 32 + wid * 8) * 64])
#define STG_A(buf, kt0) do { STGC(As, buf, 0, A, rowBase, kt0);                  \
    STGC(As, buf, 1, A, rowBase, kt0); STGC(As, buf, 2, A, rowBase, kt0);        \
    STGC(As, buf, 3, A, rowBase, kt0); } while (0)
#define STG_B(buf, kt0) do { STGC(Bs, buf, 0, Bt, colBase, kt0);                 \
    STGC(Bs, buf, 1, Bt, colBase, kt0); STGC(Bs, buf, 2, Bt, colBase, kt0);      \
    STGC(Bs, buf, 3, Bt, colBase, kt0); } while (0)

  bf16x8 afS0[4][2], afS1[4][2], bfLo[2][2], bfHi[2][2];
  const int aXor = (l15 & 7) << 4;
  const int aColB = l4 * 16;

#define LDA(buf, DST)                                                            \
  _Pragma("unroll")                                                              \
  for (int m_ = 0; m_ < 4; ++m_) {                                               \
    const int r_ = wr * 64 + m_ * 16 + l15;                                      \
    _Pragma("unroll")                                                            \
    for (int kk_ = 0; kk_ < 2; ++kk_)                                            \
      DST[m_][kk_] = *(const bf16x8*)((const char*)&As[buf][0] + r_ * 128 +      \
                                      ((kk_ * 64 + aColB) ^ aXor));              \
  }
#define LDBn(buf, DST, nb)                                                       \
  _Pragma("unroll")                                                              \
  for (int n_ = 0; n_ < 2; ++n_) {                                               \
    const int r_ = wc * 64 + ((nb) + n_) * 16 + l15;                             \
    _Pragma("unroll")                                                            \
    for (int kk_ = 0; kk_ < 2; ++kk_)                                            \
      DST[n_][kk_] = *(const bf16x8*)((const char*)&Bs[buf][0] + r_ * 128 +      \
                                      ((kk_ * 64 + aColB) ^ aXor));              \
  }
#define MMAQ(AF, BF, nb)                                                         \
  _Pragma("unroll")                                                              \
  for (int m_ = 0; m_ < 4; ++m_)                                                 \
    _Pragma("unroll")                                                            \
    for (int n_ = 0; n_ < 2; ++n_)                                               \
      _Pragma("unroll")                                                          \
      for (int kk_ = 0; kk_ < 2; ++kk_)                                          \
        acc[m_][(nb) + n_] = __builtin_amdgcn_mfma_f32_16x16x32_bf16(            \
            AF[m_][kk_], BF[n_][kk_], acc[m_][(nb) + n_], 0, 0, 0);

#define TILE(kt, AFc, AFn, cur)                                                  \
  do {                                                                           \
    const bool stA = (kt) + 2 < nk;                                              \
    const bool nxt = (kt) + 1 < nk;                                              \
    LDBn(cur, bfHi, 2);                                                          \
    if (stA) STG_A(cur, (kt) + 2);                                               \
    asm volatile("s_waitcnt lgkmcnt(4)" ::: "memory");                           \
    __builtin_amdgcn_sched_barrier(0);                                           \
    __builtin_amdgcn_s_setprio(1);                                               \
    MMAQ(AFc, bfLo, 0);                                                          \
    __builtin_amdgcn_s_setprio(0);                                               \
    __builtin_amdgcn_sched_barrier(0);                                           \
    if (stA)      { asm volatile("s_waitcnt vmcnt(4)" ::: "memory"); }           \
    else if (nxt) { asm volatile("s_waitcnt vmcnt(0)" ::: "memory"); }           \
    __builtin_amdgcn_s_barrier();                                                \
    if (nxt) { LDA(cur ^ 1, AFn); LDBn(cur ^ 1, bfLo, 0); }                      \
    if (stA) STG_B(cur, (kt) + 2);                                               \
    if (nxt) { asm volatile("s_waitcnt lgkmcnt(12)" ::: "memory"); }             \
    else     { asm volatile("s_waitcnt lgkmcnt(0)"  ::: "memory"); }             \
    __builtin_amdgcn_sched_barrier(0);                                           \
    __builtin_amdgcn_s_setprio(1);                                               \
    MMAQ(AFc, bfHi, 2);                                                          \
    __builtin_amdgcn_s_setprio(0);                                               \
    __builtin_amdgcn_sched_barrier(0);                                           \
    __builtin_amdgcn_s_barrier();                                                \
  } while (0)

  STG_A(0, 0); STG_B(0, 0);
  STG_A(1, 1); STG_B(1, 1);
  asm volatile("s_waitcnt vmcnt(8)" ::: "memory");
  __builtin_amdgcn_s_barrier();
  LDA(0, afS0); LDBn(0, bfLo, 0);

  for (int kt = 0; kt < nk; kt += 2) {
    TILE(kt,     afS0, afS1, 0);
    TILE(kt + 1, afS1, afS0, 1);
  }
#undef STGC
#undef STG_A
#undef STG_B
#undef LDA
#undef LDBn
#undef MMAQ
#undef TILE

#pragma unroll
  for (int m = 0; m < 4; ++m) {
#pragma unroll
    for (int n = 0; n < 4; ++n) {
#pragma unroll
      for (int r = 0; r < 4; ++r) {
        const int row = rowBase + wr * 64 + m * 16 + l4 * 4 + r;
        const int col = colBase + wc * 64 + n * 16 + l15;
        float v = acc[m][n][r] + bias[col];
        if (EPI == 0) {
          const int h = col / 384;
          const int sub = col - h * 384;
          const int t = sub >> 7, hd = sub & 127;
          const int bb = row >> 11, s = row & 2047;
          const size_t bh = (size_t)bb * NH + h;
          if (t == 0)      Qb[(bh * NS + s) * NHD + hd] = f2bf(v * 0.08838834764831845f);
          else if (t == 1) Kb[(bh * NS + s) * NHD + hd] = f2bf(v);
          else             Vtb[(bh * NHD + hd) * NS + s] = f2bf(v);
        } else {
          const size_t idx = (size_t)row * N + col;
          out[idx] = v + residual[idx];
        }
      }
    }
  }
}

// ---------------- flash attention: QBLK=32/wave, K in LDS (swizzled), defer-max ----
__global__ __launch_bounds__(256, 2) void attn_kernel(
    const short* __restrict__ Qb, const short* __restrict__ Kb,
    const short* __restrict__ Vtb, const float* __restrict__ alibi,
    const int* __restrict__ amask, short* __restrict__ Ob) {
  const int tid = threadIdx.x;
  const int w = tid >> 6, l = tid & 63;
  const int l15 = l & 15, l4 = l >> 4;
  const int flat = blockIdx.x;
  const int bh = flat & 31;
  const int y = (flat >> 5) & 7, z = flat >> 8;
  const int qt = z ? (15 - y) : y;
  const int bb = bh >> 4, h = bh & 15;
  const int q0 = qt * 128;
  const int qw = q0 + w * 32;
  const int NT = 2 * qt + 2;

  __shared__ float biasLds[NS];
  __shared__ short Ks[2][64 * 128];
  __shared__ short Plds[4][32 * 64];

  {
    const float* abase = alibi + (size_t)bh * NS;
    const int* mbase = amask + (size_t)bb * NS;
    for (int i = tid; i < NS; i += 256)
      biasLds[i] = mbase[i] ? abase[i] : -1e30f;
  }

  const short* kbase = Kb + (size_t)bh * NS * NHD;
  const short* vbase = Vtb + (size_t)bh * NHD * NS;

#define KSTAGE(buf, kt0) do {                                                  \
    _Pragma("unroll")                                                          \
    for (int i_ = 0; i_ < 4; ++i_) {                                           \
      const int Lb_ = w * 4096 + i_ * 1024 + l * 16;                           \
      const int row_ = Lb_ >> 8;                                               \
      const int X_ = (Lb_ & 255) ^ ((row_ & 7) << 4);                          \
      gl_lds16((const short*)((const char*)kbase + (size_t)((kt0) * 64 + row_) * 256 + X_), \
               (short*)((char*)&Ks[buf][0] + (w * 4096 + i_ * 1024)));         \
    }                                                                          \
  } while (0)

  const short* qp = Qb + ((size_t)bh * NS + qw + l15) * NHD + l4 * 8;
  bf16x8 qf[2][4];
#pragma unroll
  for (int c = 0; c < 2; ++c)
#pragma unroll
    for (int s = 0; s < 4; ++s)
      qf[c][s] = *(const bf16x8*)(qp + c * 16 * NHD + s * 32);

  f32x4 acc[2][8] = {};
  float mrun[2] = {-1e30f, -1e30f}, lrun[2] = {0.f, 0.f};

  short* myP = &Plds[w][0];
  const int pswzB = (l15 & 7) << 4;
  const int qg0 = qw + l15, qg1 = qw + 16 + l15;

  KSTAGE(0, 0);
  __syncthreads();
  int cur = 0;

  for (int t = 0; t < NT; ++t) {
    const int k0 = t << 6;
    if (t + 1 < NT) KSTAGE(cur ^ 1, t + 1);

    if (k0 <= qw + 31) {
      f32x4 sT[2][4] = {};
      __builtin_amdgcn_s_setprio(1);
#pragma unroll
      for (int p = 0; p < 4; ++p) {
        const int lrow = p * 16 + l15;
#pragma unroll
        for (int s = 0; s < 4; ++s) {
          const int lbyte = (lrow << 8) + ((s * 64 + l4 * 16) ^ ((lrow & 7) << 4));
          const bf16x8 kf = *(const bf16x8*)((const char*)&Ks[cur][0] + lbyte);
          sT[0][p] = __builtin_amdgcn_mfma_f32_16x16x32_bf16(kf, qf[0][s], sT[0][p], 0, 0, 0);
          sT[1][p] = __builtin_amdgcn_mfma_f32_16x16x32_bf16(kf, qf[1][s], sT[1][p], 0, 0, 0);
        }
      }
      __builtin_amdgcn_s_setprio(0);

      const short* vp = vbase + (size_t)l15 * NS + k0 + l4 * 8;
      bf16x8 vA[8];
#pragma unroll
      for (int t8 = 0; t8 < 8; ++t8)
        vA[t8] = *(const bf16x8*)(vp + (size_t)t8 * 16 * NS);

      const bool full = (k0 + 63 <= qw);
      float pv[2][16];
      float tmax[2] = {-1e30f, -1e30f};
#pragma unroll
      for (int p = 0; p < 4; ++p) {
        const f32x4 bvec = *(const f32x4*)&biasLds[k0 + p * 16 + l4 * 4];
#pragma unroll
        for (int r = 0; r < 4; ++r) {
          const int kg = k0 + p * 16 + l4 * 4 + r;
          float v0 = sT[0][p][r] + bvec[r];
          float v1 = sT[1][p][r] + bvec[r];
          if (!full) {
            v0 = (kg <= qg0) ? v0 : -1e30f;
            v1 = (kg <= qg1) ? v1 : -1e30f;
          }
          pv[0][p * 4 + r] = v0; pv[1][p * 4 + r] = v1;
          tmax[0] = fmaxf(tmax[0], v0);
          tmax[1] = fmaxf(tmax[1], v1);
        }
      }
#pragma unroll
      for (int c = 0; c < 2; ++c) {
        tmax[c] = fmaxf(tmax[c], __shfl_xor(tmax[c], 16, 64));
        tmax[c] = fmaxf(tmax[c], __shfl_xor(tmax[c], 32, 64));
        // T13 defer-max: only rescale when the max grew by > 8 (wave-uniform).
        if (tmax[c] > mrun[c] + 8.0f) {
          const float mnew = tmax[c];
          const float alpha = __expf(mrun[c] - mnew);
          mrun[c] = mnew;
          lrun[c] *= alpha;
#pragma unroll
          for (int t8 = 0; t8 < 8; ++t8)
#pragma unroll
            for (int r = 0; r < 4; ++r)
              acc[c][t8][r] *= alpha;
        }
        float psum = 0.f;
#pragma unroll
        for (int i = 0; i < 16; ++i) {
          pv[c][i] = __expf(pv[c][i] - mrun[c]);
          psum += pv[c][i];
        }
        psum += __shfl_xor(psum, 16, 64);
        psum += __shfl_xor(psum, 32, 64);
        lrun[c] += psum;
      }

#pragma unroll
      for (int c = 0; c < 2; ++c)
#pragma unroll
        for (int p = 0; p < 4; ++p) {
          bf16x4 pk = { (__bf16)pv[c][p * 4 + 0], (__bf16)pv[c][p * 4 + 1],
                        (__bf16)pv[c][p * 4 + 2], (__bf16)pv[c][p * 4 + 3] };
          const int byteoff = ((16 * c + l15) << 7) + (((p * 16 + l4 * 4) << 1) ^ pswzB);
          *(bf16x4*)((char*)myP + byteoff) = pk;
        }
      asm volatile("s_waitcnt lgkmcnt(0)" ::: "memory");

      bf16x8 pfA[2], pfB[2];
#pragma unroll
      for (int c = 0; c < 2; ++c)
        pfA[c] = *(const bf16x8*)((const char*)myP + ((16 * c + l15) << 7) + ((l4 * 16) ^ pswzB));
      bf16x8 vB[8];
#pragma unroll
      for (int t8 = 0; t8 < 8; ++t8)
        vB[t8] = *(const bf16x8*)(vp + 32 + (size_t)t8 * 16 * NS);
      __builtin_amdgcn_s_setprio(1);
#pragma unroll
      for (int t8 = 0; t8 < 8; ++t8) {
        acc[0][t8] = __builtin_amdgcn_mfma_f32_16x16x32_bf16(vA[t8], pfA[0], acc[0][t8], 0, 0, 0);
        acc[1][t8] = __builtin_amdgcn_mfma_f32_16x16x32_bf16(vA[t8], pfA[1], acc[1][t8], 0, 0, 0);
      }
      __builtin_amdgcn_s_setprio(0);
#pragma unroll
      for (int c = 0; c < 2; ++c)
        pfB[c] = *(const bf16x8*)((const char*)myP + ((16 * c + l15) << 7) + ((64 + l4 * 16) ^ pswzB));
      __builtin_amdgcn_s_setprio(1);
#pragma unroll
      for (int t8 = 0; t8 < 8; ++t8) {
        acc[0][t8] = __builtin_amdgcn_mfma_f32_16x16x32_bf16(vB[t8], pfB[0], acc[0][t8], 0, 0, 0);
        acc[1][t8] = __builtin_amdgcn_mfma_f32_16x16x32_bf16(vB[t8], pfB[1], acc[1][t8], 0, 0, 0);
      }
      __builtin_amdgcn_s_setprio(0);
    }

    __syncthreads();
    cur ^= 1;
  }
#undef KSTAGE

#pragma unroll
  for (int c = 0; c < 2; ++c) {
    const float inv = (lrun[c] > 0.f) ? 1.0f / lrun[c] : 0.f;
    short* obase = Ob + ((size_t)bb * NS + qw + 16 * c + l15) * ND + h * NHD + l4 * 4;
#pragma unroll
    for (int t8 = 0; t8 < 8; ++t8) {
      bf16x4 o = { (__bf16)(acc[c][t8][0] * inv), (__bf16)(acc[c][t8][1] * inv),
                   (__bf16)(acc[c][t8][2] * inv), (__bf16)(acc[c][t8][3] * inv) };
      *(bf16x4*)&obase[t8 * 16] = o;
    }
  }
}

extern "C" void kernel_launch(void* const* d_in, const int* in_sizes, int n_in,
                              void* d_out, int out_size, void* d_ws, size_t ws_size,
                              hipStream_t stream) {
  const float* hidden   = (const float*)d_in[0];
  const float* residual = (const float*)d_in[1];
  const float* alibi    = (const float*)d_in[2];
  const float* W_qkv    = (const float*)d_in[3];
  const float* b_qkv    = (const float*)d_in[4];
  const float* W_o      = (const float*)d_in[5];
  const float* b_o      = (const float*)d_in[6];
  const int*   amask    = (const int*)d_in[7];
  float* out = (float*)d_out;

  char* p = (char*)d_ws;
  short* Abuf  = (short*)p; p += (size_t)NM * ND * 2;
  short* WqkvT = (short*)p; p += (size_t)NQKV * ND * 2;
  short* WoT   = (short*)p; p += (size_t)ND * ND * 2;
  short* Qb    = (short*)p; p += (size_t)NB * NH * NS * NHD * 2;
  short* Kb    = (short*)p; p += (size_t)NB * NH * NS * NHD * 2;
  short* Vtb   = (short*)p; p += (size_t)NB * NH * NS * NHD * 2;
  short* Ob    = (short*)p; p += (size_t)NM * ND * 2;

  prep_kernel<<<dim3(12288), 256, 0, stream>>>(hidden, Abuf, W_qkv, WqkvT, W_o, WoT);
  gemm_kernel<0><<<dim3((NM / 128) * (NQKV / 128)), 256, 0, stream>>>(
      Abuf, WqkvT, ND, NQKV, NQKV / 128, b_qkv, Qb, Kb, Vtb, nullptr, nullptr);
  attn_kernel<<<dim3(512), 256, 0, stream>>>(Qb, Kb, Vtb, alibi, amask, Ob);
  gemm_kernel<1><<<dim3((NM / 128) * (ND / 128)), 256, 0, stream>>>(
      Ob, WoT, ND, ND, ND / 128, b_o, nullptr, nullptr, nullptr, residual, out);
}